// Round 8
// baseline (2928.449 us; speedup 1.0000x reference)
//
#include <hip/hip_runtime.h>

#define B_ 8
#define N_ 32768
#define S_ 1024
#define C_ 96
#define M_ 32              // blocks per batch (flat all-to-all key exchange)
#define T_ 64              // ONE wave per block: no __syncthreads, no LDS
#define PPB (N_ / M_)      // 1024 points per block
#define PPT (PPB / T_)     // 16 points per thread
#define PK (PPT / 2)       // 8 float2 pairs per thread

typedef float f2v __attribute__((ext_vector_type(2)));
typedef unsigned long long u64;
typedef unsigned int u32;

// Key = (float_bits(dist) << 32) | ~idx. dist >= 0 -> bits unsigned-monotone;
// ~idx makes u64-max prefer the SMALLEST index on ties. Key is the payload ->
// relaxed atomics, no fences. Fresh row of M_ keys per (batch, step): no ABA.

// d_out layout (float32, concatenated):
//   [0, B*S*3)                      new_xyz  (B,S,3)
//   [B*S*3, B*S*3+B*C*S)            new_fea  (B,C,S)  <- doubles as slot scratch
//   [B*S*3+B*C*S, +B*S)             indices  (B,S) as float

__global__ __launch_bounds__(T_)
__attribute__((amdgpu_waves_per_eu(1, 2)))
void fps_kernel(
    const float* __restrict__ xyz,   // (B, N, 3)
    float* __restrict__ out,
    u64* __restrict__ parts)         // (B_*S_, M_) key slots, pre-zeroed
{
#pragma clang fp contract(off)
  const int blk  = blockIdx.x;
  const int b    = blk & 7;          // batch (blocks of a batch share an XCD, heuristic)
  const int m    = blk >> 3;         // sub-block 0..M_-1
  const int lane = threadIdx.x;      // one wave
  const float* xb = xyz + (size_t)b * N_ * 3;
  const int base = m * PPB;

  float* out_xyz = out;
  float* out_idx = out + (size_t)B_*S_*3 + (size_t)B_*C_*S_;

  // Coords AND running min-dists fully in registers (48 + 16 VGPRs).
  f2v X[PK], Y[PK], Z[PK], D[PK];
  #pragma unroll
  for (int k = 0; k < PK; ++k) {
    const int g0 = base + (2*k)   * T_ + lane;
    const int g1 = base + (2*k+1) * T_ + lane;
    X[k] = (f2v){xb[g0*3+0], xb[g1*3+0]};
    Y[k] = (f2v){xb[g0*3+1], xb[g1*3+1]};
    Z[k] = (f2v){xb[g0*3+2], xb[g1*3+2]};
    D[k] = (f2v){1e10f, 1e10f};
  }
  #pragma unroll
  for (int k = 0; k < PK; ++k) {
    asm volatile("" : "+v"(X[k]), "+v"(Y[k]), "+v"(Z[k]));  // not rematerializable
  }

  // Loop-carried current point: index + coords (coords arrive via shuffle,
  // never through a serial post-sync memory fetch).
  int   cur = 0;
  float cx = xb[0], cy = xb[1], cz = xb[2];

  for (int s = 0; s < S_; ++s) {
    if (m == 0 && lane == 0) {
      out_idx[(size_t)b*S_ + s] = (float)cur;
      float* o = out_xyz + ((size_t)b*S_ + s)*3;
      o[0] = cx; o[1] = cy; o[2] = cz;
    }
    const f2v c2x = (f2v){cx, cx};
    const f2v c2y = (f2v){cy, cy};
    const f2v c2z = (f2v){cz, cz};

    // Exact IEEE ((dx^2+dy^2)+dz^2), no contraction; per-thread argmax with
    // first-index tie-break (ascending j, strict >; idx(2k) < idx(2k+1)).
    float bv = -1.0f;
    int   bj = 0;
    #pragma unroll
    for (int k = 0; k < PK; ++k) {
      const f2v dx = X[k] - c2x;
      const f2v dy = Y[k] - c2y;
      const f2v dz = Z[k] - c2z;
      const f2v d  = (dx*dx + dy*dy) + dz*dz;
      f2v nd;
      nd.x = fminf(D[k].x, d.x);
      nd.y = fminf(D[k].y, d.y);
      D[k] = nd;
      if (nd.x > bv) { bv = nd.x; bj = 2*k;   }
      if (nd.y > bv) { bv = nd.y; bj = 2*k+1; }
    }
    const int bg = base + (bj << 6) + lane;    // global point index (T_ == 64)

    // Local pack + 6-level butterfly max (all 64 lanes distinct indices).
    u64 key = ((u64)__float_as_uint(bv) << 32) | (u32)(~bg);
    #pragma unroll
    for (int off = 32; off > 0; off >>= 1) {
      const u64 ok = __shfl_xor(key, off);
      if (ok > key) key = ok;
    }

    // Publish partial; poll all 32 partials (tight spin, keys never 0).
    u64* row = parts + ((size_t)(b * S_ + s) << 5);
    if (lane == 0) {
      __hip_atomic_store(&row[m], key, __ATOMIC_RELAXED, __HIP_MEMORY_SCOPE_AGENT);
    }
    u64 k0;
    do {
      k0 = __hip_atomic_load(&row[lane & 31], __ATOMIC_RELAXED, __HIP_MEMORY_SCOPE_AGENT);
    } while (__ballot(k0 != 0) != ~0ull);

    // SPECULATIVE coord loads for every lane's candidate — in flight while
    // the combine butterfly runs (xyz is IC-resident; latency overlapped).
    const int ci = (int)(u32)(~(u32)k0);
    const float lx = xb[ci*3+0];
    const float ly = xb[ci*3+1];
    const float lz = xb[ci*3+2];

    // 5-level combine (offset-32 partners hold identical polled keys).
    u64 k = k0;
    #pragma unroll
    for (int off = 16; off > 0; off >>= 1) {
      const u64 ok = __shfl_xor(k, off);
      if (ok > k) k = ok;
    }

    // Winning lane (lanes i and i+32 mirror -> lowest set bit is < 32) and
    // coordinate broadcast from it; next-step state fully in registers.
    const u64 wm = __ballot(k0 == k);
    const int ws = (int)__builtin_ctzll(wm);
    cx = __shfl(lx, ws);
    cy = __shfl(ly, ws);
    cz = __shfl(lz, ws);
    cur = (int)(u32)(~(u32)k);
  }
}

__global__ void gather_fea_kernel(
    const float* __restrict__ feat,   // (B, C, N)
    const float* __restrict__ idxf,   // (B, S) float indices (in d_out)
    float* __restrict__ out_fea)      // (B, C, S)
{
  const int t = blockIdx.x * blockDim.x + threadIdx.x;
  if (t >= B_ * C_ * S_) return;
  const int s  = t & (S_ - 1);
  const int bc = t >> 10;           // S_ == 1024
  const int c  = bc % C_;
  const int b  = bc / C_;
  const int idx = (int)idxf[(size_t)b * S_ + s];
  out_fea[t] = feat[((size_t)b * C_ + c) * (size_t)N_ + idx];
}

extern "C" void kernel_launch(void* const* d_in, const int* in_sizes, int n_in,
                              void* d_out, int out_size, void* d_ws, size_t ws_size,
                              hipStream_t stream) {
  const float* xyz  = (const float*)d_in[0];   // (B,N,3)
  const float* feat = (const float*)d_in[1];   // (B,C,N)
  float* out = (float*)d_out;

  float* out_fea = out + (size_t)B_ * S_ * 3;
  float* out_idx = out + (size_t)B_ * S_ * 3 + (size_t)B_ * C_ * S_;
  (void)d_ws; (void)ws_size; (void)in_sizes; (void)n_in; (void)out_size;

  // Slot scratch lives in the out_fea region (3 MB >= 2 MB needed); it is
  // fully overwritten by gather_fea_kernel afterwards. Zero it (poisoned 0xAA).
  u64* parts = (u64*)out_fea;
  hipMemsetAsync(parts, 0, (size_t)B_ * S_ * M_ * sizeof(u64), stream);

  fps_kernel<<<B_ * M_, T_, 0, stream>>>(xyz, out, parts);

  const int total = B_ * C_ * S_;
  gather_fea_kernel<<<(total + 255) / 256, 256, 0, stream>>>(feat, out_idx, out_fea);
}